// Round 5
// baseline (332.700 us; speedup 1.0000x reference)
//
#include <hip/hip_runtime.h>
#include <hip/hip_bf16.h>
#include <cstdint>
#include <cstddef>

#define NN     50000
#define NE     800000
#define FIN    128
#define CAP    64       // per-node bucket capacity; P(Poisson(16)>64) ~ 5e-19
#define NBIN   784      // bins of 64 dst nodes: bin = dst>>6
#define CAPBIN 1280     // slots per bin segment; Poisson(1024)+6sigma ~ 1216
#define SB     157      // scatter blocks (pinned)
#define SCT    1024     // scatter/prep block threads (pinned, R13 win)
#define EPT    5        // edges per thread (157*1024*5 = 803840 >= NE)
#define PREPB  786      // prep blocks of 1024 thr x 8 floats (786*8192 >= 6432768)
#define DREP   4        // diagnostic amplification factor

using bf16x8 = __attribute__((ext_vector_type(8))) short;
using f32x4  = __attribute__((ext_vector_type(4))) float;
using f32x2  = __attribute__((ext_vector_type(2))) float;

// ---- workspace layout (production, unchanged from R2-best) ----
static const size_t OFF_CUR  = 0;          // int[784]  bincursor (final = bin counts)
static const size_t OFF_PART = 800;        // int[784*1280 = 1,003,520]
static const size_t S_HB  = 2008640;       // bf16[6,400,000]
static const size_t S_HNB = 8408640;       // bf16[6,400,000]
static const size_t S_WB  = 14808640;      // bf16[32,768]
static const size_t S_HF8 = 14841408;      // fp8 e4m3 [6,400,000] as 3,200,000 shorts
// production end = 36.1 MB.  ws = 256 MiB -> diag scratch at byte offsets:
#define B_CUR2  (48u << 20)   // int[DREP*784]
#define B_PART2 (49u << 20)   // int[784*1280] = 4.0 MB
#define B_HNBD  (56u << 20)   // bf16[6,400,000] = 12.8 MB
#define B_OUTD  (80u << 20)   // float[DREP][6,400,000] = 102.4 MB (ends 182.4 MB)

__device__ __forceinline__ unsigned f2bf(float f) {
    unsigned u = __float_as_uint(f);
    return (u + 0x7FFFu + ((u >> 16) & 1u)) >> 16;   // RNE
}

// ================= PRODUCTION (exact R2-best, 135.6 us config) =================

__global__ __launch_bounds__(SCT) void k_ps(
    const float* __restrict__ h, const float* __restrict__ W,
    unsigned* __restrict__ hB, unsigned* __restrict__ WB,
    uint2* __restrict__ hF8,
    const int* __restrict__ src, const int* __restrict__ dst,
    int* __restrict__ bincursor, int* __restrict__ part)
{
    __shared__ int lcur[NBIN];
    __shared__ int lofs[NBIN];
    __shared__ int gbase[NBIN];
    __shared__ int wsum[16];
    __shared__ int ebuf[EPT * SCT];
    int blk = blockIdx.x, tid = threadIdx.x;

    if (blk >= SB) {
        int i = (blk - SB) * SCT + tid;
        size_t e = (size_t)i * 8;
        const float* s;
        unsigned* d;
        bool isH = (e < 6400000);
        if (isH) { s = h + e; d = hB + e / 2; }
        else if (e < 6400000 + 32768) { s = W + (e - 6400000); d = WB + (e - 6400000) / 2; }
        else return;
        float4 a = *(const float4*)s;
        float4 b = *(const float4*)(s + 4);
        uint4 o;
        o.x = f2bf(a.x) | (f2bf(a.y) << 16);
        o.y = f2bf(a.z) | (f2bf(a.w) << 16);
        o.z = f2bf(b.x) | (f2bf(b.y) << 16);
        o.w = f2bf(b.z) | (f2bf(b.w) << 16);
        *(uint4*)d = o;
        if (isH) {
            int w0 = __builtin_amdgcn_cvt_pk_fp8_f32(a.x, a.y, 0, false);
            w0     = __builtin_amdgcn_cvt_pk_fp8_f32(a.z, a.w, w0, true);
            int w1 = __builtin_amdgcn_cvt_pk_fp8_f32(b.x, b.y, 0, false);
            w1     = __builtin_amdgcn_cvt_pk_fp8_f32(b.z, b.w, w1, true);
            hF8[e / 8] = make_uint2((unsigned)w0, (unsigned)w1);
        }
        return;
    }

    int b = blk;
    if (tid < NBIN) lcur[tid] = 0;
    __syncthreads();
    int e0 = b * (EPT * SCT);
    int pk[EPT], rk[EPT];
#pragma unroll
    for (int k = 0; k < EPT; ++k) {
        int e = e0 + k * SCT + tid;
        if (e < NE) {
            int d = dst[e];
            int s = src[e];
            int bin = d >> 6;
            pk[k] = s | ((d & 63) << 16) | (bin << 22);
            rk[k] = atomicAdd(&lcur[bin], 1);
        } else {
            pk[k] = -1;
        }
    }
    __syncthreads();

    int lane = tid & 63, wid = tid >> 6;
    int c = (tid < NBIN) ? lcur[tid] : 0;
    int v = c;
#pragma unroll
    for (int dd = 1; dd < 64; dd <<= 1) {
        int n = __shfl_up(v, dd);
        if (lane >= dd) v += n;
    }
    if (lane == 63) wsum[wid] = v;
    __syncthreads();
    if (wid == 0) {
        int s16 = (lane < 16) ? wsum[lane] : 0;
        int wv = s16;
#pragma unroll
        for (int dd = 1; dd < 16; dd <<= 1) {
            int n = __shfl_up(wv, dd);
            if (lane >= dd) wv += n;
        }
        if (lane < 16) wsum[lane] = wv - s16;
    }
    __syncthreads();
    if (tid < NBIN) {
        lofs[tid]  = v - c + wsum[wid];
        gbase[tid] = c ? atomicAdd(&bincursor[tid], c) : 0;
    }
    __syncthreads();

#pragma unroll
    for (int k = 0; k < EPT; ++k) {
        if (pk[k] != -1) {
            int bin = ((unsigned)pk[k]) >> 22;
            ebuf[lofs[bin] + rk[k]] = pk[k];
        }
    }
    __syncthreads();

    int total = min(NE - e0, EPT * SCT);
    for (int i = tid; i < total; i += SCT) {
        int e = ebuf[i];
        int bin = ((unsigned)e) >> 22;
        int g = gbase[bin] + (i - lofs[bin]);
        if (g < CAPBIN)
            part[bin * CAPBIN + g] = e & 0x3FFFFF;
    }
}

__device__ __forceinline__ f32x2 fp8lo(unsigned u) {
    return __builtin_amdgcn_cvt_pk_f32_fp8((int)u, false);
}
__device__ __forceinline__ f32x2 fp8hi(unsigned u) {
    return __builtin_amdgcn_cvt_pk_f32_fp8((int)u, true);
}

__device__ __forceinline__ void aggbin_body(
    int blk, int tid,
    const int* __restrict__ part, const int* __restrict__ bincursor,
    const unsigned* __restrict__ hF8u, unsigned* __restrict__ hNB2,
    int* ldeg, unsigned short* bucketL)
{
    int bin = blk >> 2, sub = blk & 3;
    if (tid < 16) ldeg[tid] = 0;
    __syncthreads();
    int cnt = min(bincursor[bin], CAPBIN);
    const int* pj = part + bin * CAPBIN;
    for (int i = tid; i < cnt; i += 256) {
        int v = pj[i];
        int local = (v >> 16) & 63;
        if ((local >> 4) == sub) {
            int l16 = local & 15;
            int slot = atomicAdd(&ldeg[l16], 1);
            if (slot < CAP) bucketL[l16 * CAP + slot] = (unsigned short)v;
        }
    }
    __syncthreads();
    int wave = tid >> 6, lane = tid & 63;
    int halfid = lane >> 5;
    int l32 = lane & 31;
#pragma unroll
    for (int t = 0; t < 4; ++t) {
        int l16 = wave * 4 + t;
        int n = bin * 64 + (sub << 4) + l16;
        if (n >= NN) continue;
        int d = ldeg[l16];
        int c2 = min(d, CAP);
        const unsigned short* bp = &bucketL[l16 * CAP];
        float a0 = 0.f, a1 = 0.f, a2 = 0.f, a3 = 0.f;
        int i = 0;
        for (; i + 16 <= c2; i += 16) {
            unsigned uu[8];
#pragma unroll
            for (int j = 0; j < 8; ++j)
                uu[j] = hF8u[(size_t)bp[i + 2 * j + halfid] * 32 + l32];
#pragma unroll
            for (int j = 0; j < 8; ++j) {
                f32x2 lo = fp8lo(uu[j]);
                f32x2 hi = fp8hi(uu[j]);
                a0 += lo[0]; a1 += lo[1]; a2 += hi[0]; a3 += hi[1];
            }
        }
        for (; i < c2; i += 2) {
            int e = i + halfid;
            unsigned u = 0;
            if (e < c2) u = hF8u[(size_t)bp[e] * 32 + l32];
            f32x2 lo = fp8lo(u);
            f32x2 hi = fp8hi(u);
            a0 += lo[0]; a1 += lo[1]; a2 += hi[0]; a3 += hi[1];
        }
        a0 += __shfl_xor(a0, 32);
        a1 += __shfl_xor(a1, 32);
        a2 += __shfl_xor(a2, 32);
        a3 += __shfl_xor(a3, 32);
        if (halfid == 0) {
            float inv = 1.0f / fmaxf((float)d, 1.0f);
            unsigned p0 = f2bf(a0 * inv) | (f2bf(a1 * inv) << 16);
            unsigned p1 = f2bf(a2 * inv) | (f2bf(a3 * inv) << 16);
            *(uint2*)(hNB2 + (size_t)n * 64 + l32 * 2) = make_uint2(p0, p1);
        }
    }
}

__global__ __launch_bounds__(256) void k_aggbin(const int* __restrict__ part,
                                                const int* __restrict__ bincursor,
                                                const unsigned* __restrict__ hF8u,
                                                unsigned* __restrict__ hNB2) {
    __shared__ int ldeg[16];
    __shared__ unsigned short bucketL[16 * CAP];
    aggbin_body(blockIdx.x, threadIdx.x, part, bincursor, hF8u, hNB2, ldeg, bucketL);
}

__device__ __forceinline__ void gemm_body(
    int bx, int jbase, int tid,
    const short* __restrict__ hB, const short* __restrict__ hNB,
    const short* __restrict__ WB, const float* __restrict__ bias,
    float* __restrict__ out, short* WL)
{
    for (int g = tid; g < 2048; g += 256) {
        int row = g >> 5;
        int c   = g & 31;
        int cs  = (c + row) & 31;
        bf16x8 v = *(const bf16x8*)(WB + (size_t)(jbase + row) * 256 + c * 8);
        *(bf16x8*)(&WL[row * 256 + cs * 8]) = v;
    }
    __syncthreads();

    const int wave = tid >> 6;
    const int lane = tid & 63;
    const int q    = lane >> 4;
    const int ln   = lane & 15;
    const int mbase = (bx * 4 + wave) * 16;
    int node = mbase + ln;
    if (node >= NN) node = NN - 1;

    f32x4 acc[4];
#pragma unroll
    for (int t = 0; t < 4; ++t) acc[t] = (f32x4){0.f, 0.f, 0.f, 0.f};

#pragma unroll
    for (int k0 = 0; k0 < 8; ++k0) {
        int ck = k0 * 4 + q;
        const short* ap = (k0 < 4) ? (hB  + (size_t)node * 128 + ck * 8)
                                   : (hNB + (size_t)node * 128 + (ck - 16) * 8);
        bf16x8 afr = *(const bf16x8*)ap;
#pragma unroll
        for (int t = 0; t < 4; ++t) {
            int row = t * 16 + ln;
            int cs  = (ck + row) & 31;
            bf16x8 bfr = *(const bf16x8*)(&WL[row * 256 + cs * 8]);
            acc[t] = __builtin_amdgcn_mfma_f32_16x16x32_bf16(afr, bfr, acc[t], 0, 0, 0);
        }
    }

#pragma unroll
    for (int t = 0; t < 4; ++t) {
        float bv = bias[jbase + t * 16 + ln];
#pragma unroll
        for (int r = 0; r < 4; ++r) {
            int m = mbase + q * 4 + r;
            if (m < NN)
                out[(size_t)m * FIN + jbase + t * 16 + ln] = acc[t][r] + bv;
        }
    }
}

__global__ __launch_bounds__(256) void k_gemm(
    const short* __restrict__ hB, const short* __restrict__ hNB,
    const short* __restrict__ WB, const float* __restrict__ bias,
    float* __restrict__ out)
{
    __shared__ short WL[16384];
    gemm_body(blockIdx.x, blockIdx.y * 64, threadIdx.x, hB, hNB, WB, bias, out, WL);
}

// ================= DIAGNOSTICS (x4 grid-amplified copies, scratch-only) =========

__global__ __launch_bounds__(SCT) void k_prep_diag(
    const float* __restrict__ h, const float* __restrict__ W,
    unsigned* __restrict__ hB, unsigned* __restrict__ WB,
    uint2* __restrict__ hF8)
{
    int tid = threadIdx.x;
    int i = (int)(blockIdx.x % PREPB) * SCT + tid;   // same-value rewrites: benign
    size_t e = (size_t)i * 8;
    const float* s;
    unsigned* d;
    bool isH = (e < 6400000);
    if (isH) { s = h + e; d = hB + e / 2; }
    else if (e < 6400000 + 32768) { s = W + (e - 6400000); d = WB + (e - 6400000) / 2; }
    else return;
    float4 a = *(const float4*)s;
    float4 b = *(const float4*)(s + 4);
    uint4 o;
    o.x = f2bf(a.x) | (f2bf(a.y) << 16);
    o.y = f2bf(a.z) | (f2bf(a.w) << 16);
    o.z = f2bf(b.x) | (f2bf(b.y) << 16);
    o.w = f2bf(b.z) | (f2bf(b.w) << 16);
    *(uint4*)d = o;
    if (isH) {
        int w0 = __builtin_amdgcn_cvt_pk_fp8_f32(a.x, a.y, 0, false);
        w0     = __builtin_amdgcn_cvt_pk_fp8_f32(a.z, a.w, w0, true);
        int w1 = __builtin_amdgcn_cvt_pk_fp8_f32(b.x, b.y, 0, false);
        w1     = __builtin_amdgcn_cvt_pk_fp8_f32(b.z, b.w, w1, true);
        hF8[e / 8] = make_uint2((unsigned)w0, (unsigned)w1);
    }
}

__global__ __launch_bounds__(SCT) void k_scatter_diag(
    const int* __restrict__ src, const int* __restrict__ dst,
    int* __restrict__ bincursor2, int* __restrict__ part2)
{
    __shared__ int lcur[NBIN];
    __shared__ int lofs[NBIN];
    __shared__ int gbase[NBIN];
    __shared__ int wsum[16];
    __shared__ int ebuf[EPT * SCT];
    int rep = blockIdx.x / SB;
    int b   = blockIdx.x % SB;
    int tid = threadIdx.x;
    int* bc = bincursor2 + rep * NBIN;   // per-rep cursor copy (pre-zeroed)
    // part2 raced across reps with different-but-valid values; never read.

    if (tid < NBIN) lcur[tid] = 0;
    __syncthreads();
    int e0 = b * (EPT * SCT);
    int pk[EPT], rk[EPT];
#pragma unroll
    for (int k = 0; k < EPT; ++k) {
        int e = e0 + k * SCT + tid;
        if (e < NE) {
            int d = dst[e];
            int s = src[e];
            int bin = d >> 6;
            pk[k] = s | ((d & 63) << 16) | (bin << 22);
            rk[k] = atomicAdd(&lcur[bin], 1);
        } else {
            pk[k] = -1;
        }
    }
    __syncthreads();

    int lane = tid & 63, wid = tid >> 6;
    int c = (tid < NBIN) ? lcur[tid] : 0;
    int v = c;
#pragma unroll
    for (int dd = 1; dd < 64; dd <<= 1) {
        int n = __shfl_up(v, dd);
        if (lane >= dd) v += n;
    }
    if (lane == 63) wsum[wid] = v;
    __syncthreads();
    if (wid == 0) {
        int s16 = (lane < 16) ? wsum[lane] : 0;
        int wv = s16;
#pragma unroll
        for (int dd = 1; dd < 16; dd <<= 1) {
            int n = __shfl_up(wv, dd);
            if (lane >= dd) wv += n;
        }
        if (lane < 16) wsum[lane] = wv - s16;
    }
    __syncthreads();
    if (tid < NBIN) {
        lofs[tid]  = v - c + wsum[wid];
        gbase[tid] = c ? atomicAdd(&bc[tid], c) : 0;
    }
    __syncthreads();

#pragma unroll
    for (int k = 0; k < EPT; ++k) {
        if (pk[k] != -1) {
            int bin = ((unsigned)pk[k]) >> 22;
            ebuf[lofs[bin] + rk[k]] = pk[k];
        }
    }
    __syncthreads();

    int total = min(NE - e0, EPT * SCT);
    for (int i = tid; i < total; i += SCT) {
        int e = ebuf[i];
        int bin = ((unsigned)e) >> 22;
        int g = gbase[bin] + (i - lofs[bin]);
        if (g < CAPBIN)
            part2[bin * CAPBIN + g] = e & 0x3FFFFF;
    }
}

__global__ __launch_bounds__(256) void k_aggbin_diag(const int* __restrict__ part,
                                                     const int* __restrict__ bincursor,
                                                     const unsigned* __restrict__ hF8u,
                                                     unsigned* __restrict__ hNBd) {
    __shared__ int ldeg[16];
    __shared__ unsigned short bucketL[16 * CAP];
    aggbin_body(blockIdx.x % (NBIN * 4), threadIdx.x, part, bincursor, hF8u, hNBd,
                ldeg, bucketL);
}

__global__ __launch_bounds__(256) void k_gemm_diag(
    const short* __restrict__ hB, const short* __restrict__ hNB,
    const short* __restrict__ WB, const float* __restrict__ bias,
    float* __restrict__ outd)
{
    __shared__ short WL[16384];
    float* o = outd + (size_t)blockIdx.z * NN * FIN;
    gemm_body(blockIdx.x, blockIdx.y * 64, threadIdx.x, hB, hNB, WB, bias, o, WL);
}

extern "C" void kernel_launch(void* const* d_in, const int* in_sizes, int n_in,
                              void* d_out, int out_size, void* d_ws, size_t ws_size,
                              hipStream_t stream) {
    const float* h   = (const float*)d_in[0];
    const int*   src = (const int*)d_in[1];
    const int*   dst = (const int*)d_in[2];
    const float* W   = (const float*)d_in[3];
    const float* b   = (const float*)d_in[4];
    float* out = (float*)d_out;

    int*   wsI = (int*)d_ws;
    short* wsS = (short*)d_ws;
    char*  wsB = (char*)d_ws;

    int* bincursor = wsI + OFF_CUR;
    int* part      = wsI + OFF_PART;
    short* hB      = wsS + S_HB;
    short* hNB     = wsS + S_HNB;
    short* WB      = wsS + S_WB;
    const unsigned* hF8u = (const unsigned*)(wsS + S_HF8);

    int*   bincursor2 = (int*)(wsB + B_CUR2);
    int*   part2      = (int*)(wsB + B_PART2);
    short* hNBd       = (short*)(wsB + B_HNBD);
    float* outd       = (float*)(wsB + B_OUTD);

    // ---- production (exact R2-best) ----
    hipMemsetAsync(bincursor, 0, NBIN * sizeof(int), stream);
    hipMemsetAsync(bincursor2, 0, DREP * NBIN * sizeof(int), stream);
    k_ps     <<<SB + PREPB, SCT, 0, stream>>>(
        h, W, (unsigned*)hB, (unsigned*)WB, (uint2*)(wsS + S_HF8),
        src, dst, bincursor, part);
    k_aggbin <<<NBIN * 4, 256, 0, stream>>>(part, bincursor, hF8u, (unsigned*)hNB);
    k_gemm   <<<dim3((NN + 63) / 64, 2), 256, 0, stream>>>(hB, hNB, WB, b, out);

    // ---- diagnostics (x4 each, scratch-only; this round only) ----
    k_prep_diag    <<<PREPB * DREP, SCT, 0, stream>>>(
        h, W, (unsigned*)hB, (unsigned*)WB, (uint2*)(wsS + S_HF8));
    k_scatter_diag <<<SB * DREP, SCT, 0, stream>>>(src, dst, bincursor2, part2);
    k_aggbin_diag  <<<NBIN * 4 * DREP, 256, 0, stream>>>(part, bincursor, hF8u,
                                                         (unsigned*)hNBd);
    k_gemm_diag    <<<dim3((NN + 63) / 64, 2, DREP), 256, 0, stream>>>(
        hB, hNB, WB, b, outd);
}

// Round 6
// 137.311 us; speedup vs baseline: 2.4230x; 2.4230x over previous
//
#include <hip/hip_runtime.h>
#include <hip/hip_bf16.h>
#include <cstdint>
#include <cstddef>

#define NN     50000
#define NE     800000
#define FIN    128
#define CAP    64       // per-node bucket capacity; P(Poisson(16)>64) ~ 5e-19
#define NBIN   784      // bins of 64 dst nodes: bin = dst>>6
#define CAPBIN 1280     // slots per bin segment; Poisson(1024)+6sigma ~ 1216
#define SB     157      // scatter blocks (pinned)
#define SCT    1024     // scatter/prep block threads (pinned, R13 win)
#define EPT    5        // edges per thread (157*1024*5 = 803840 >= NE)
#define PREPB  786      // prep blocks of 1024 thr x 8 floats (786*8192 >= 6432768)

using bf16x8 = __attribute__((ext_vector_type(8))) short;
using f32x4  = __attribute__((ext_vector_type(4))) float;
using f32x2  = __attribute__((ext_vector_type(2))) float;

// ---- workspace layout ----
static const size_t OFF_CUR  = 0;          // int[784]  bincursor (final = bin counts)
static const size_t OFF_PART = 800;        // int[784*1280 = 1,003,520]
static const size_t S_HB  = 2008640;       // bf16[6,400,000]
static const size_t S_HNB = 8408640;       // bf16[6,400,000]
static const size_t S_WB  = 14808640;      // bf16[32,768]
static const size_t S_HF8 = 14841408;      // fp8 e4m3 [6,400,000] as 3,200,000 shorts
// end = 18,041,408 shorts = 36.1 MB

__device__ __forceinline__ unsigned f2bf(float f) {
    unsigned u = __float_as_uint(f);
    return (u + 0x7FFFu + ((u >> 16) & 1u)) >> 16;   // RNE
}

// ---- K1: fused scatter (blocks 0..SB-1) + prep (rest) — R2-best exact ----
__global__ __launch_bounds__(SCT) void k_ps(
    const float* __restrict__ h, const float* __restrict__ W,
    unsigned* __restrict__ hB, unsigned* __restrict__ WB,
    uint2* __restrict__ hF8,
    const int* __restrict__ src, const int* __restrict__ dst,
    int* __restrict__ bincursor, int* __restrict__ part)
{
    __shared__ int lcur[NBIN];
    __shared__ int lofs[NBIN];
    __shared__ int gbase[NBIN];
    __shared__ int wsum[16];
    __shared__ int ebuf[EPT * SCT];
    int blk = blockIdx.x, tid = threadIdx.x;

    if (blk >= SB) {
        int i = (blk - SB) * SCT + tid;
        size_t e = (size_t)i * 8;
        const float* s;
        unsigned* d;
        bool isH = (e < 6400000);
        if (isH) { s = h + e; d = hB + e / 2; }
        else if (e < 6400000 + 32768) { s = W + (e - 6400000); d = WB + (e - 6400000) / 2; }
        else return;
        float4 a = *(const float4*)s;
        float4 b = *(const float4*)(s + 4);
        uint4 o;
        o.x = f2bf(a.x) | (f2bf(a.y) << 16);
        o.y = f2bf(a.z) | (f2bf(a.w) << 16);
        o.z = f2bf(b.x) | (f2bf(b.y) << 16);
        o.w = f2bf(b.z) | (f2bf(b.w) << 16);
        *(uint4*)d = o;
        if (isH) {
            int w0 = __builtin_amdgcn_cvt_pk_fp8_f32(a.x, a.y, 0, false);
            w0     = __builtin_amdgcn_cvt_pk_fp8_f32(a.z, a.w, w0, true);
            int w1 = __builtin_amdgcn_cvt_pk_fp8_f32(b.x, b.y, 0, false);
            w1     = __builtin_amdgcn_cvt_pk_fp8_f32(b.z, b.w, w1, true);
            hF8[e / 8] = make_uint2((unsigned)w0, (unsigned)w1);
        }
        return;
    }

    int b = blk;
    if (tid < NBIN) lcur[tid] = 0;
    __syncthreads();
    int e0 = b * (EPT * SCT);
    int pk[EPT], rk[EPT];
#pragma unroll
    for (int k = 0; k < EPT; ++k) {
        int e = e0 + k * SCT + tid;
        if (e < NE) {
            int d = dst[e];
            int s = src[e];
            int bin = d >> 6;
            pk[k] = s | ((d & 63) << 16) | (bin << 22);
            rk[k] = atomicAdd(&lcur[bin], 1);
        } else {
            pk[k] = -1;
        }
    }
    __syncthreads();

    int lane = tid & 63, wid = tid >> 6;
    int c = (tid < NBIN) ? lcur[tid] : 0;
    int v = c;
#pragma unroll
    for (int dd = 1; dd < 64; dd <<= 1) {
        int n = __shfl_up(v, dd);
        if (lane >= dd) v += n;
    }
    if (lane == 63) wsum[wid] = v;
    __syncthreads();
    if (wid == 0) {
        int s16 = (lane < 16) ? wsum[lane] : 0;
        int wv = s16;
#pragma unroll
        for (int dd = 1; dd < 16; dd <<= 1) {
            int n = __shfl_up(wv, dd);
            if (lane >= dd) wv += n;
        }
        if (lane < 16) wsum[lane] = wv - s16;
    }
    __syncthreads();
    if (tid < NBIN) {
        lofs[tid]  = v - c + wsum[wid];
        gbase[tid] = c ? atomicAdd(&bincursor[tid], c) : 0;
    }
    __syncthreads();

#pragma unroll
    for (int k = 0; k < EPT; ++k) {
        if (pk[k] != -1) {
            int bin = ((unsigned)pk[k]) >> 22;
            ebuf[lofs[bin] + rk[k]] = pk[k];
        }
    }
    __syncthreads();

    int total = min(NE - e0, EPT * SCT);
    for (int i = tid; i < total; i += SCT) {
        int e = ebuf[i];
        int bin = ((unsigned)e) >> 22;
        int g = gbase[bin] + (i - lofs[bin]);
        if (g < CAPBIN)
            part[bin * CAPBIN + g] = e & 0x3FFFFF;
    }
}

__device__ __forceinline__ f32x2 fp8lo(unsigned u) {
    return __builtin_amdgcn_cvt_pk_f32_fp8((int)u, false);
}
__device__ __forceinline__ f32x2 fp8hi(unsigned u) {
    return __builtin_amdgcn_cvt_pk_f32_fp8((int)u, true);
}

// ---- K2: per-quarter-bin LDS bucket + paired gather-mean over fp8 rows ----
// R6 change (VALU cut; counters: VALUBusy 58%, MfmaUtil 0 -> VALU-bound):
//  (1) 32-bit gather offsets -> v_lshl_add_u32 + saddr global_load
//      (was 64-bit size_t mul/add chain per load)
//  (2) packed f32x2 accumulators -> v_pk_add_f32 (was 4 scalar v_add_f32)
// Per-element add sequence unchanged -> bit-identical output.
__global__ __launch_bounds__(256) void k_aggbin(const int* __restrict__ part,
                                                const int* __restrict__ bincursor,
                                                const unsigned* __restrict__ hF8u,
                                                unsigned* __restrict__ hNB2) {
    __shared__ int ldeg[16];
    __shared__ unsigned short bucketL[16 * CAP];   // 2 KB
    int blk = blockIdx.x, tid = threadIdx.x;
    int bin = blk >> 2, sub = blk & 3;
    if (tid < 16) ldeg[tid] = 0;
    __syncthreads();
    int cnt = min(bincursor[bin], CAPBIN);
    const int* pj = part + bin * CAPBIN;
    for (int i = tid; i < cnt; i += 256) {
        int v = pj[i];
        int local = (v >> 16) & 63;
        if ((local >> 4) == sub) {
            int l16 = local & 15;
            int slot = atomicAdd(&ldeg[l16], 1);
            if (slot < CAP) bucketL[l16 * CAP + slot] = (unsigned short)v;
        }
    }
    __syncthreads();
    int wave = tid >> 6, lane = tid & 63;
    int halfid = lane >> 5;        // which edge of the pair
    int l32 = lane & 31;           // feature group: 4 fp8 feats 4*l32..+3
#pragma unroll
    for (int t = 0; t < 4; ++t) {
        int l16 = wave * 4 + t;
        int n = bin * 64 + (sub << 4) + l16;
        if (n >= NN) continue;
        int d = ldeg[l16];
        int c2 = min(d, CAP);
        const unsigned short* bp = &bucketL[l16 * CAP];
        f32x2 s01 = (f32x2){0.f, 0.f};
        f32x2 s23 = (f32x2){0.f, 0.f};
        int i = 0;
        for (; i + 16 <= c2; i += 16) {
            unsigned uu[8];
#pragma unroll
            for (int j = 0; j < 8; ++j) {
                unsigned off = ((unsigned)bp[i + 2 * j + halfid] << 5) + (unsigned)l32;
                uu[j] = hF8u[off];          // 32-bit voffset -> saddr form
            }
#pragma unroll
            for (int j = 0; j < 8; ++j) {
                s01 += fp8lo(uu[j]);        // v_pk_add_f32
                s23 += fp8hi(uu[j]);
            }
        }
        for (; i < c2; i += 2) {
            int e = i + halfid;
            unsigned u = 0;
            if (e < c2) {
                unsigned off = ((unsigned)bp[e] << 5) + (unsigned)l32;
                u = hF8u[off];
            }
            s01 += fp8lo(u);
            s23 += fp8hi(u);
        }
        float a0 = s01[0], a1 = s01[1], a2 = s23[0], a3 = s23[1];
        a0 += __shfl_xor(a0, 32);
        a1 += __shfl_xor(a1, 32);
        a2 += __shfl_xor(a2, 32);
        a3 += __shfl_xor(a3, 32);
        if (halfid == 0) {
            float inv = 1.0f / fmaxf((float)d, 1.0f);
            unsigned p0 = f2bf(a0 * inv) | (f2bf(a1 * inv) << 16);
            unsigned p1 = f2bf(a2 * inv) | (f2bf(a3 * inv) << 16);
            *(uint2*)(hNB2 + (size_t)n * 64 + l32 * 2) = make_uint2(p0, p1);
        }
    }
}

// ---- K3: out = [hB | hNB] @ W^T + b via MFMA, LDS-staged W, j-split (R2 exact) ----
__global__ __launch_bounds__(256) void k_gemm(
    const short* __restrict__ hB, const short* __restrict__ hNB,
    const short* __restrict__ WB, const float* __restrict__ bias,
    float* __restrict__ out)
{
    __shared__ short WL[16384];   // 32 KB
    const int tid = threadIdx.x;
    const int jbase = blockIdx.y * 64;

    for (int g = tid; g < 2048; g += 256) {
        int row = g >> 5;          // 0..63
        int c   = g & 31;          // k-chunk
        int cs  = (c + row) & 31;  // swizzled
        bf16x8 v = *(const bf16x8*)(WB + (size_t)(jbase + row) * 256 + c * 8);
        *(bf16x8*)(&WL[row * 256 + cs * 8]) = v;
    }
    __syncthreads();

    const int wave = tid >> 6;
    const int lane = tid & 63;
    const int q    = lane >> 4;
    const int ln   = lane & 15;
    const int mbase = (blockIdx.x * 4 + wave) * 16;
    int node = mbase + ln;
    if (node >= NN) node = NN - 1;

    f32x4 acc[4];
#pragma unroll
    for (int t = 0; t < 4; ++t) acc[t] = (f32x4){0.f, 0.f, 0.f, 0.f};

#pragma unroll
    for (int k0 = 0; k0 < 8; ++k0) {
        int ck = k0 * 4 + q;
        const short* ap = (k0 < 4) ? (hB  + (size_t)node * 128 + ck * 8)
                                   : (hNB + (size_t)node * 128 + (ck - 16) * 8);
        bf16x8 afr = *(const bf16x8*)ap;
#pragma unroll
        for (int t = 0; t < 4; ++t) {
            int row = t * 16 + ln;
            int cs  = (ck + row) & 31;
            bf16x8 bfr = *(const bf16x8*)(&WL[row * 256 + cs * 8]);
            acc[t] = __builtin_amdgcn_mfma_f32_16x16x32_bf16(afr, bfr, acc[t], 0, 0, 0);
        }
    }

#pragma unroll
    for (int t = 0; t < 4; ++t) {
        float bv = bias[jbase + t * 16 + ln];
#pragma unroll
        for (int r = 0; r < 4; ++r) {
            int m = mbase + q * 4 + r;
            if (m < NN)
                out[(size_t)m * FIN + jbase + t * 16 + ln] = acc[t][r] + bv;
        }
    }
}

extern "C" void kernel_launch(void* const* d_in, const int* in_sizes, int n_in,
                              void* d_out, int out_size, void* d_ws, size_t ws_size,
                              hipStream_t stream) {
    const float* h   = (const float*)d_in[0];
    const int*   src = (const int*)d_in[1];
    const int*   dst = (const int*)d_in[2];
    const float* W   = (const float*)d_in[3];
    const float* b   = (const float*)d_in[4];
    float* out = (float*)d_out;

    int*   wsI = (int*)d_ws;
    short* wsS = (short*)d_ws;

    int* bincursor = wsI + OFF_CUR;
    int* part      = wsI + OFF_PART;
    short* hB      = wsS + S_HB;
    short* hNB     = wsS + S_HNB;
    short* WB      = wsS + S_WB;
    const unsigned* hF8u = (const unsigned*)(wsS + S_HF8);

    hipMemsetAsync(bincursor, 0, NBIN * sizeof(int), stream);
    k_ps     <<<SB + PREPB, SCT, 0, stream>>>(
        h, W, (unsigned*)hB, (unsigned*)WB, (uint2*)(wsS + S_HF8),
        src, dst, bincursor, part);
    k_aggbin <<<NBIN * 4, 256, 0, stream>>>(part, bincursor, hF8u, (unsigned*)hNB);
    k_gemm   <<<dim3((NN + 63) / 64, 2), 256, 0, stream>>>(hB, hNB, WB, b, out);
}